// Round 11
// baseline (69.759 us; speedup 1.0000x reference)
//
#include <hip/hip_runtime.h>

// ArithmeticCompute: circle-encoded modular arithmetic over PRIMES.
// out[3][B*S][10][2] = {add, sub, mul} on the unit circle.
//
// R11 structure (delta vs R10):
//  - Block = 128 threads = 2 waves, owns 64 pairs. Wave 0 = prime subset
//    A {2,13,17,29} (~1256 ops), wave 1 = subset B {3,5,7,11,19,23}
//    (~1230 ops), both over the block's 64 pair-rows. 1024 blocks = 4
//    co-resident blocks/CU (LDS 16.9 KB, VGPR ~84 under the (128,2) cap)
//    -> one block's load/store phases overlap another's compute.
//  - Barriers are raw `s_waitcnt lgkmcnt(0); s_barrier` (inline asm):
//    LDS producer/consumer ordering needs only lgkmcnt + barrier. This
//    keeps the phase-1 add/sub GLOBAL stores in flight across the
//    barrier instead of the vmcnt(0) drain __syncthreads would emit
//    (nobody reads those stores; ~10.5 MB no longer serializes).
//
// Carried lessons: R3/R7 — VGPR caps of 48/64 cause catastrophic scratch
// spill of the p29 body (~80 live floats); keep cap >= ~120.
// R5 — LDS tiles must be native float2 (aligned b64 ops).
// R10 — staging extent = pairs*10 float2 exactly (block 64 pairs -> 640).
//
// mul per (pair, prime): quartet-folded softmax outer product (R6):
// pair residues i<->p-i, j<->p-j; A[k]=W[k]+W[p-k] += ua*ub,
// B[k]=W[k]-W[p-k] +-= va*vb; out needs only sum(A*cos), sum(B*sin).
// Pair loop = (p-1)^2/2 FMAs.

#define TEMP_LOG2E 1442.6950408889634f  // softmax_temperature * log2(e)

// LDS-only barrier: wait own LDS ops, sync waves; do NOT drain vmem stores.
#define BARRIER_LDS() __asm__ volatile("s_waitcnt lgkmcnt(0)\n\ts_barrier" ::: "memory")

constexpr double PI_D = 3.14159265358979323846264338327950288;

constexpr double tay_cos(double x) {
    double x2 = x * x, term = 1.0, sum = 1.0;
    for (int k = 1; k <= 15; ++k) { term *= -x2 / double((2 * k - 1) * (2 * k)); sum += term; }
    return sum;
}
constexpr double tay_sin(double x) {
    double x2 = x * x, term = x, sum = x;
    for (int k = 1; k <= 15; ++k) { term *= -x2 / double((2 * k) * (2 * k + 1)); sum += term; }
    return sum;
}
constexpr double ang_red(int r, int P) {  // 2*pi*r/P reduced to [-pi, pi]
    double x = 2.0 * PI_D * double(r) / double(P);
    return (x > PI_D) ? x - 2.0 * PI_D : x;
}

template <int P> struct TabS { float c[P]; float s[P]; };
template <int P>
constexpr TabS<P> make_tabs() {
    TabS<P> t{};
    for (int r = 0; r < P; ++r) {
        t.c[r] = (float)(double(TEMP_LOG2E) * tay_cos(ang_red(r, P)));
        t.s[r] = (float)(double(TEMP_LOG2E) * tay_sin(ang_red(r, P)));
    }
    return t;
}
template <int P> struct TabE { float c[P / 2 + 1]; float s[P / 2 + 1]; };
template <int P>
constexpr TabE<P> make_tabe() {
    TabE<P> t{};
    for (int k = 0; k <= P / 2; ++k) {
        t.c[k] = (float)tay_cos(ang_red(k, P));
        t.s[k] = (float)tay_sin(ang_red(k, P));
    }
    return t;
}

template <int P>
__device__ __forceinline__ void mul_prime(float ca, float sa, float cb, float sb,
                                          float& oc, float& os) {
    static_assert(P % 2 == 1, "generic path requires odd P");
    constexpr int H = (P - 1) / 2;
    constexpr TabS<P> T = make_tabs<P>();
    constexpr TabE<P> E = make_tabe<P>();

    // Pass 1: maxes of the scaled similarities (overflow guard).
    float ma = -1e30f, mb = -1e30f;
#pragma unroll
    for (int r = 0; r < P; ++r) {
        ma = fmaxf(ma, ca * T.c[r] + sa * T.s[r]);
        mb = fmaxf(mb, cb * T.c[r] + sb * T.s[r]);
    }

    // Pass 2: b-side folded softmax numerators.
    float eb0 = __builtin_amdgcn_exp2f(cb * T.c[0] - mb);  // T.s[0] == 0
    float Sb = eb0;
    float ub[H], vb[H];
#pragma unroll
    for (int j = 1; j <= H; ++j) {
        float e1 = __builtin_amdgcn_exp2f(cb * T.c[j] + sb * T.s[j] - mb);
        float e2 = __builtin_amdgcn_exp2f(cb * T.c[P - j] + sb * T.s[P - j] - mb);
        Sb += e1 + e2;
        ub[j - 1] = e1 + e2;
        vb[j - 1] = e1 - e2;
    }

    // Pass 3: a-side outer loop (recomputed, nothing stored) + pair loop.
    float A[H], Bacc[H];
#pragma unroll
    for (int k = 0; k < H; ++k) { A[k] = 0.f; Bacc[k] = 0.f; }

    float ea0 = __builtin_amdgcn_exp2f(ca * T.c[0] - ma);
    float Sa = ea0;
#pragma unroll
    for (int i = 1; i <= H; ++i) {
        float f1 = __builtin_amdgcn_exp2f(ca * T.c[i] + sa * T.s[i] - ma);
        float f2 = __builtin_amdgcn_exp2f(ca * T.c[P - i] + sa * T.s[P - i] - ma);
        Sa += f1 + f2;
        const float ua = f1 + f2, va = f1 - f2;
#pragma unroll
        for (int j = 1; j <= H; ++j) {
            const int k0 = (i * j) % P;            // compile-time after unroll
            const int kr = (k0 <= H) ? k0 : P - k0;
            A[kr - 1] = fmaf(ua, ub[j - 1], A[kr - 1]);
            if (k0 <= H) Bacc[kr - 1] = fmaf(va,  vb[j - 1], Bacc[kr - 1]);
            else         Bacc[kr - 1] = fmaf(-va, vb[j - 1], Bacc[kr - 1]);
        }
    }

    // Zero row/column: contributes only to W[0].
    const float W0 = ea0 * Sb + eb0 * (Sa - ea0);

    // Epilogue: re-encode. cos is even in k, sin is odd.
    float accC = W0, accS = 0.f;
#pragma unroll
    for (int k = 1; k <= H; ++k) {
        accC = fmaf(A[k - 1],    E.c[k], accC);
        accS = fmaf(Bacc[k - 1], E.s[k], accS);
    }
    const float inv = 1.0f / (Sa * Sb);
    oc = accC * inv;
    os = accS * inv;
}

// P = 2: closed form (templates (1,0), (-1,0); sin terms vanish).
template <>
__device__ __forceinline__ void mul_prime<2>(float ca, float sa, float cb, float sb,
                                             float& oc, float& os) {
    const float ka = ca * TEMP_LOG2E, kb = cb * TEMP_LOG2E;
    const float ma = fabsf(ka), mb = fabsf(kb);
    const float ea0 = __builtin_amdgcn_exp2f(ka - ma);
    const float ea1 = __builtin_amdgcn_exp2f(-ka - ma);
    const float eb0 = __builtin_amdgcn_exp2f(kb - mb);
    const float eb1 = __builtin_amdgcn_exp2f(-kb - mb);
    const float Sa = ea0 + ea1, Sb = eb0 + eb1;
    const float W0 = ea0 * Sb + eb0 * Sa - ea0 * eb0;
    const float W1 = ea1 * eb1;
    oc = (W0 - W1) / (Sa * Sb);
    os = 0.f;
}

__global__ __launch_bounds__(128, 2) void arith_kernel(const float* __restrict__ a,
                                                       const float* __restrict__ b,
                                                       float* __restrict__ out,
                                                       int n_pairs) {
    // 64 pairs x 11 float2 slots (10 primes + pad). 16.9 KB total.
    __shared__ float2 ta[64 * 11], tb[64 * 11], om[64 * 11];

    const int t = threadIdx.x;                 // 0..127
    const int gbase = blockIdx.x * 640;        // block base in float2
    const int planef2 = n_pairs * 10;          // plane size in float2
    float2* o = (float2*)out;

    // Phase 1: coalesced load + stage (extent 640 float2 = 5 iters x 128).
    // add/sub are elementwise: computed in registers, stored coalesced now;
    // these stores stay in flight across the LDS-only barrier below.
#pragma unroll
    for (int it = 0; it < 5; ++it) {
        const int idx = it * 128 + t;          // 0..639
        const int pr = idx / 10, of = idx - pr * 10;
        const int sl = pr * 11 + of;
        const float2 av = ((const float2*)a)[gbase + idx];
        const float2 bv = ((const float2*)b)[gbase + idx];
        ta[sl] = av;
        tb[sl] = bv;
        const float pcc = av.x * bv.x, pss = av.y * bv.y;
        const float psc = av.y * bv.x, pcs = av.x * bv.y;
        o[gbase + idx]           = make_float2(pcc - pss, psc + pcs);  // add
        o[planef2 + gbase + idx] = make_float2(pcc + pss, psc - pcs);  // sub
    }
    BARRIER_LDS();

    // Phase 2: wave 0 -> subset A, wave 1 -> subset B, both on rows 0..63.
    {
        const int lane = t & 63;
        const int rb = lane * 11;

#define DO_PRIME(P, OFI)                                                     \
        {                                                                    \
            const float2 av = ta[rb + (OFI)];                                \
            const float2 bv = tb[rb + (OFI)];                                \
            float oc, os;                                                    \
            mul_prime<P>(av.x, av.y, bv.x, bv.y, oc, os);                    \
            om[rb + (OFI)] = make_float2(oc, os);                            \
        }

        if (t < 64) {
            // Subset A: {2, 13, 17, 29} ~= 1256 ops
            DO_PRIME(29, 9)
            DO_PRIME(17, 6)
            DO_PRIME(13, 5)
            DO_PRIME(2, 0)
        } else {
            // Subset B: {3, 5, 7, 11, 19, 23} ~= 1230 ops
            DO_PRIME(23, 8)
            DO_PRIME(19, 7)
            DO_PRIME(11, 4)
            DO_PRIME(7, 3)
            DO_PRIME(5, 2)
            DO_PRIME(3, 1)
        }
#undef DO_PRIME
    }
    BARRIER_LDS();

    // Phase 3: coalesced LDS -> global for the mul plane (5 iters).
#pragma unroll
    for (int it = 0; it < 5; ++it) {
        const int idx = it * 128 + t;
        const int pr = idx / 10, of = idx - pr * 10;
        o[2 * planef2 + gbase + idx] = om[pr * 11 + of];
    }
}

extern "C" void kernel_launch(void* const* d_in, const int* in_sizes, int n_in,
                              void* d_out, int out_size, void* d_ws, size_t ws_size,
                              hipStream_t stream) {
    const float* a = (const float*)d_in[0];
    const float* b = (const float*)d_in[1];
    float* out = (float*)d_out;
    const int n_pairs = in_sizes[0] / 20;   // B*S = 65536 (multiple of 64)
    const int n_blocks = n_pairs / 64;      // 1024 blocks of 128 threads

    dim3 block(128);
    dim3 grid(n_blocks);
    arith_kernel<<<grid, block, 0, stream>>>(a, b, out, n_pairs);
}